// Round 4
// baseline (170.840 us; speedup 1.0000x reference)
//
#include <hip/hip_runtime.h>

// NFLinear equivariant layer, closed-form decomposition.
// out0[a,b,:] = w_ih[a,b,:]@th0[0] + A0C[a,:] + B0[b,:]
// out1[a,b,:] = Y[a,b,:]@th1[13] + Y[b,a,:]@th1[11] + A1C[a,:] + B1[b,:] + (a==b)*DD1[a,:]
// out2[b,:]   = vectors(b)@th2 + scalars   (written by k_vec)
//
// k_stage1: single pass over each W; row means direct, col sums as per-block
//           partials (LDS-accumulated, deterministic).
// k_vec:    thetas in LDS; per-band col-partial reduction; grand means; scalar
//           projections; vector terms; out2.
// k_out:    both big output streams.

#define N0 784
#define N1 512
#define RPB 4                 // rows per stage1 block
#define NB_IH (N0 / RPB)      // 196
#define NB_HH (N1 / RPB)      // 128

__device__ __forceinline__ float4 f4add(float4 a, float4 b) {
  a.x += b.x; a.y += b.y; a.z += b.z; a.w += b.w; return a;
}

// grid 324: [0,196) w_ih bands; [196,324) w_hh bands (+ diag).
__global__ __launch_bounds__(256)
void k_stage1(const float* __restrict__ wih, const float* __restrict__ whh,
              float* __restrict__ rm_ih, float* __restrict__ rm_hh,
              float* __restrict__ d_hh,
              float* __restrict__ part_ih, float* __restrict__ part_hh) {
  __shared__ float4 colacc[2048];        // 32 KB: col sums of this 4-row band
  __shared__ float4 redAll[RPB][256];    // 16 KB: row-sum trees
  int t = threadIdx.x, blk = blockIdx.x;
  bool is_hh = blk >= NB_IH;
  const float* W = is_hh ? whh : wih;
  float* rm      = is_hh ? rm_hh : rm_ih;
  float* part    = is_hh ? part_hh : part_ih;
  int pblk = is_hh ? blk - NB_IH : blk;
  int r0 = pblk * RPB;

  for (int j = t; j < 2048; j += 256) colacc[j] = make_float4(0.f, 0.f, 0.f, 0.f);
  // colacc[j] only ever touched by thread t == j%256: no barrier needed here.
  #pragma unroll
  for (int r = 0; r < RPB; r++) {
    const float4* row = (const float4*)(W + (size_t)(r0 + r) * 8192);
    float4 acc = make_float4(0.f, 0.f, 0.f, 0.f);
    for (int j = t; j < 2048; j += 256) {
      float4 v = row[j];
      colacc[j] = f4add(colacc[j], v);
      acc = f4add(acc, v);
    }
    redAll[r][t] = acc;
  }
  __syncthreads();
  #pragma unroll
  for (int s = 128; s >= 4; s >>= 1) {
    if (t < s) {
      #pragma unroll
      for (int r = 0; r < RPB; r++) redAll[r][t] = f4add(redAll[r][t], redAll[r][t + s]);
    }
    __syncthreads();
  }
  if (t < 16) {  // thread t: row r=t>>2, quad q=t&3 (lane-class mod 4 == quad)
    int r = t >> 2, q = t & 3;
    float4 m = redAll[r][q];
    const float s = 1.f / 512.f;
    ((float4*)(rm + (r0 + r) * 16))[q] = make_float4(m.x * s, m.y * s, m.z * s, m.w * s);
  }
  if (is_hh && t < 64) {
    int r = t >> 4, ci = t & 15;
    d_hh[(r0 + r) * 16 + ci] = whh[(size_t)(r0 + r) * 8192 + (r0 + r) * 16 + ci];
  }
  float4* p4 = (float4*)(part + (size_t)pblk * 8192);
  for (int j = t; j < 2048; j += 256) p4[j] = colacc[j];
}

// grid 49
__global__ __launch_bounds__(256)
void k_vec(const float* __restrict__ rm_ih, const float* __restrict__ rm_hh,
           const float* __restrict__ d_hh, const float* __restrict__ bvec,
           const float* __restrict__ part_ih, const float* __restrict__ part_hh,
           const float* __restrict__ th0, const float* __restrict__ bias0,
           const float* __restrict__ th1, const float* __restrict__ bias1,
           const float* __restrict__ th2, const float* __restrict__ bias2,
           float* __restrict__ A0C, float* __restrict__ B0,
           float* __restrict__ A1C, float* __restrict__ B1,
           float* __restrict__ DD1, float* __restrict__ out2) {
  __shared__ float th[11520];   // th0 @0 (2816), th1 @2816 (6400), th2 @9216 (2304)
  __shared__ float4 red[256];
  __shared__ float gv[4][16];
  __shared__ float sc[64];
  __shared__ float cmih_s[16][16];
  __shared__ float cmhh_s[16][16];
  int t = threadIdx.x;
  {
    float4* t4 = (float4*)th;
    const float4* s0 = (const float4*)th0;
    const float4* s1 = (const float4*)th1;
    const float4* s2 = (const float4*)th2;
    for (int j = t; j < 704; j += 256) t4[j] = s0[j];
    for (int j = t; j < 1600; j += 256) t4[704 + j] = s1[j];
    for (int j = t; j < 576; j += 256) t4[2304 + j] = s2[j];
  }
  int il = t >> 4, co = t & 15;
  int i0 = blockIdx.x * 16;
  // band col-mean reduction from partials (only bands with i < 512)
  if (i0 < N1) {
    int col = i0 + il;
    float s1 = 0.f;
    #pragma unroll 4
    for (int p = 0; p < NB_IH; p++) s1 += part_ih[(size_t)p * 8192 + col * 16 + co];
    cmih_s[il][co] = s1 * (1.f / 784.f);
    float s2 = 0.f;
    #pragma unroll 4
    for (int p = 0; p < NB_HH; p++) s2 += part_hh[(size_t)p * 8192 + col * 16 + co];
    cmhh_s[il][co] = s2 * (1.f / 512.f);
  }
  int q = t & 3, g = t >> 2;
  // gv[0]=mean rm_ih, gv[1]=mean d_hh, gv[2]=mean rm_hh, gv[3]=mean bvec
  {
    float4 acc = make_float4(0.f, 0.f, 0.f, 0.f);
    for (int a = g; a < N0; a += 64) acc = f4add(acc, ((const float4*)rm_ih)[a * 4 + q]);
    red[t] = acc; __syncthreads();
    #pragma unroll
    for (int s = 128; s >= 4; s >>= 1) { if (t < s) red[t] = f4add(red[t], red[t + s]); __syncthreads(); }
    if (t < 4) {
      float4 m = red[t];
      gv[0][t * 4 + 0] = m.x / 784.f; gv[0][t * 4 + 1] = m.y / 784.f;
      gv[0][t * 4 + 2] = m.z / 784.f; gv[0][t * 4 + 3] = m.w / 784.f;
    }
    __syncthreads();
  }
  const float* srcs[3] = { d_hh, rm_hh, bvec };
  #pragma unroll
  for (int v = 0; v < 3; v++) {
    float4 acc = make_float4(0.f, 0.f, 0.f, 0.f);
    for (int a = g; a < N1; a += 64) acc = f4add(acc, ((const float4*)srcs[v])[a * 4 + q]);
    red[t] = acc; __syncthreads();
    #pragma unroll
    for (int s = 128; s >= 4; s >>= 1) { if (t < s) red[t] = f4add(red[t], red[t + s]); __syncthreads(); }
    if (t < 4) {
      float4 m = red[t];
      gv[v + 1][t * 4 + 0] = m.x / 512.f; gv[v + 1][t * 4 + 1] = m.y / 512.f;
      gv[v + 1][t * 4 + 2] = m.z / 512.f; gv[v + 1][t * 4 + 3] = m.w / 512.f;
    }
    __syncthreads();
  }
  // scalar projections: C0, C1, E1, S2
  {
    int j = t >> 4, o = j * 16 + co;
    float g0v = gv[0][j], dm = gv[1][j], gh = gv[2][j], mv = gv[3][j];
    float4 p;
    p.x = g0v * th[768 + o]         + dm * th[1280 + o]        + gh * th[2048 + o]        + mv * th[2560 + o];
    p.y = g0v * th[2816 + 1024 + o] + dm * th[2816 + 2304 + o] + gh * th[2816 + 4864 + o] + mv * th[2816 + 6144 + o];
    p.z = g0v * th[2816 + 512 + o]  + dm * th[2816 + 1792 + o] + gh * th[2816 + 4096 + o] + mv * th[2816 + 5632 + o];
    p.w = g0v * th[9216 + 256 + o]  + dm * th[9216 + 768 + o]  + gh * th[9216 + 1536 + o] + mv * th[9216 + 2048 + o];
    red[t] = p; __syncthreads();
    #pragma unroll
    for (int s = 128; s >= 16; s >>= 1) { if (t < s) red[t] = f4add(red[t], red[t + s]); __syncthreads(); }
    if (t < 16) {
      float4 a = red[t];
      sc[t] = a.x + bias0[t];
      sc[16 + t] = a.y + bias1[t];
      sc[32 + t] = a.z;              // E1: no bias
      sc[48 + t] = a.w + bias2[t];
    }
    __syncthreads();
  }
  // vector terms
  int idx = blockIdx.x * 256 + t;
  int i = i0 + il;
  float a0 = sc[co];
  {
    const float4* r4 = (const float4*)(rm_ih + i * 16);
    #pragma unroll
    for (int kq = 0; kq < 4; kq++) {
      float4 r = r4[kq];
      float vr[4] = { r.x, r.y, r.z, r.w };
      #pragma unroll
      for (int e = 0; e < 4; e++) a0 += vr[e] * th[256 + (kq * 4 + e) * 16 + co];
    }
  }
  A0C[idx] = a0;
  if (i < N1) {
    float b0a = 0.f, a1 = sc[16 + co], b1a = 0.f, dd = sc[32 + co], o2 = sc[48 + co];
    const float4* d4 = (const float4*)(d_hh + i * 16);
    const float4* r4 = (const float4*)(rm_hh + i * 16);
    const float4* v4 = (const float4*)(bvec + i * 16);
    #pragma unroll
    for (int kq = 0; kq < 4; kq++) {
      float4 dq = d4[kq], rq = r4[kq], vq = v4[kq];
      float vd[4] = { dq.x, dq.y, dq.z, dq.w };
      float vr[4] = { rq.x, rq.y, rq.z, rq.w };
      float vb[4] = { vq.x, vq.y, vq.z, vq.w };
      #pragma unroll
      for (int e = 0; e < 4; e++) {
        int k = kq * 4 + e;
        int o = k * 16 + co;
        float cmi = cmih_s[il][k], cm = cmhh_s[il][k];
        float d = vd[e], r = vr[e], v = vb[e];
        b0a += cmi * th[512 + o]         + d * th[1024 + o]        + r * th[1536 + o]        + cm * th[1792 + o]        + v * th[2304 + o];
        a1  += cmi * th[2816 + 768 + o]  + d * th[2816 + 2048 + o] + r * th[2816 + 4352 + o] + cm * th[2816 + 4608 + o] + v * th[2816 + 5888 + o];
        b1a += cmi * th[2816 + 256 + o]  + d * th[2816 + 1536 + o] + r * th[2816 + 3072 + o] + cm * th[2816 + 3840 + o] + v * th[2816 + 5376 + o];
        dd  += cmi * th[2816 + 0 + o]    + d * th[2816 + 1280 + o] + r * th[2816 + 2560 + o] + cm * th[2816 + 3584 + o] + v * th[2816 + 5120 + o];
        o2  += cmi * th[9216 + 0 + o]    + d * th[9216 + 512 + o]  + r * th[9216 + 1024 + o] + cm * th[9216 + 1280 + o] + v * th[9216 + 1792 + o];
      }
    }
    B0[idx] = b0a; A1C[idx] = a1; B1[idx] = b1a; DD1[idx] = dd; out2[idx] = o2;
  }
}

// grid 2048: blocks [0,1024) stream out0; [1024,2048) stream out1.
__global__ __launch_bounds__(256)
void k_out(const float* __restrict__ wih, const float* __restrict__ whh,
           const float* __restrict__ th0, const float* __restrict__ th1,
           const float* __restrict__ A0C, const float* __restrict__ B0,
           const float* __restrict__ A1C, const float* __restrict__ B1,
           const float* __restrict__ DD1,
           float* __restrict__ out0, float* __restrict__ out1) {
  if (blockIdx.x < 1024) {
    int tid = blockIdx.x * 256 + threadIdx.x;
    int q = tid & 3;
    int slot = tid >> 2;
    const int nslots = (1024 * 256) >> 2;
    float4 tq[16];
    #pragma unroll
    for (int k = 0; k < 16; k++) tq[k] = *(const float4*)(th0 + k * 16 + q * 4);
    for (int p = slot; p < N0 * N1; p += nslots) {
      const float4* row = (const float4*)(wih + (size_t)p * 16);
      float4 r0 = row[0], r1 = row[1], r2 = row[2], r3 = row[3];
      int a = p >> 9, bb = p & 511;
      float4 acc = *(const float4*)(A0C + a * 16 + q * 4);
      float4 b4 = *(const float4*)(B0 + bb * 16 + q * 4);
      acc.x += b4.x; acc.y += b4.y; acc.z += b4.z; acc.w += b4.w;
      float wv[16] = { r0.x, r0.y, r0.z, r0.w, r1.x, r1.y, r1.z, r1.w,
                       r2.x, r2.y, r2.z, r2.w, r3.x, r3.y, r3.z, r3.w };
      #pragma unroll
      for (int k = 0; k < 16; k++) {
        acc.x += wv[k] * tq[k].x; acc.y += wv[k] * tq[k].y;
        acc.z += wv[k] * tq[k].z; acc.w += wv[k] * tq[k].w;
      }
      *(float4*)(out0 + (size_t)p * 16 + q * 4) = acc;
    }
  } else {
    int tid = (blockIdx.x - 1024) * 256 + threadIdx.x;
    int q = tid & 7;
    int slot = tid >> 3;
    const int nslots = (1024 * 256) >> 3;
    float2 tA[16], tB[16];
    #pragma unroll
    for (int k = 0; k < 16; k++) {
      tA[k] = *(const float2*)(th1 + 13 * 256 + k * 16 + q * 2);
      tB[k] = *(const float2*)(th1 + 11 * 256 + k * 16 + q * 2);
    }
    for (int p = slot; p < N1 * N1; p += nslots) {
      int a = p >> 9, b = p & 511;
      const float4* ra = (const float4*)(whh + (size_t)p * 16);
      const float4* rt = (const float4*)(whh + (size_t)((b << 9) | a) * 16);
      float4 a0 = ra[0], a1v = ra[1], a2 = ra[2], a3 = ra[3];
      float4 t0 = rt[0], t1v = rt[1], t2 = rt[2], t3 = rt[3];
      float2 acc = *(const float2*)(A1C + a * 16 + q * 2);
      float2 bb = *(const float2*)(B1 + b * 16 + q * 2);
      acc.x += bb.x; acc.y += bb.y;
      if (a == b) {
        float2 dd = *(const float2*)(DD1 + a * 16 + q * 2);
        acc.x += dd.x; acc.y += dd.y;
      }
      float ya[16] = { a0.x, a0.y, a0.z, a0.w, a1v.x, a1v.y, a1v.z, a1v.w,
                       a2.x, a2.y, a2.z, a2.w, a3.x, a3.y, a3.z, a3.w };
      float yt[16] = { t0.x, t0.y, t0.z, t0.w, t1v.x, t1v.y, t1v.z, t1v.w,
                       t2.x, t2.y, t2.z, t2.w, t3.x, t3.y, t3.z, t3.w };
      #pragma unroll
      for (int k = 0; k < 16; k++) {
        acc.x += ya[k] * tA[k].x + yt[k] * tB[k].x;
        acc.y += ya[k] * tA[k].y + yt[k] * tB[k].y;
      }
      *(float2*)(out1 + (size_t)p * 16 + q * 2) = acc;
    }
  }
}

extern "C" void kernel_launch(void* const* d_in, const int* in_sizes, int n_in,
                              void* d_out, int out_size, void* d_ws, size_t ws_size,
                              hipStream_t stream) {
  const float* w_ih = (const float*)d_in[0];
  const float* w_hh = (const float*)d_in[1];
  const float* bvec = (const float*)d_in[2];
  const float *th0, *bias0, *th1, *bias1, *th2, *bias2;
  if (n_in >= 9 && in_sizes[4] == 16) {  // dict order
    th0 = (const float*)d_in[3]; bias0 = (const float*)d_in[4];
    th1 = (const float*)d_in[5]; bias1 = (const float*)d_in[6];
    th2 = (const float*)d_in[7]; bias2 = (const float*)d_in[8];
  } else {  // signature order
    th0 = (const float*)d_in[3]; th1 = (const float*)d_in[4]; th2 = (const float*)d_in[5];
    bias0 = (const float*)d_in[6]; bias1 = (const float*)d_in[7]; bias2 = (const float*)d_in[8];
  }
  float* ws      = (float*)d_ws;
  float* rm_ih   = ws;                        // 12544
  float* rm_hh   = rm_ih + 12544;             // 8192
  float* d_hh    = rm_hh + 8192;              // 8192
  float* A0C     = d_hh + 8192;               // 12544
  float* B0      = A0C + 12544;               // 8192
  float* A1C     = B0 + 8192;                 // 8192
  float* B1      = A1C + 8192;                // 8192
  float* DD1     = B1 + 8192;                 // 8192
  float* part_ih = DD1 + 8192;                // 196*8192
  float* part_hh = part_ih + NB_IH * 8192;    // 128*8192
  float* out0 = (float*)d_out;
  float* out1 = out0 + (size_t)N0 * N1 * 16;
  float* out2 = out1 + (size_t)N1 * N1 * 16;

  hipLaunchKernelGGL(k_stage1, dim3(NB_IH + NB_HH), dim3(256), 0, stream,
                     w_ih, w_hh, rm_ih, rm_hh, d_hh, part_ih, part_hh);
  hipLaunchKernelGGL(k_vec, dim3(49), dim3(256), 0, stream,
                     rm_ih, rm_hh, d_hh, bvec, part_ih, part_hh,
                     th0, bias0, th1, bias1, th2, bias2,
                     A0C, B0, A1C, B1, DD1, out2);
  hipLaunchKernelGGL(k_out, dim3(2048), dim3(256), 0, stream,
                     w_ih, w_hh, th0, th1, A0C, B0, A1C, B1, DD1, out0, out1);
}

// Round 5
// 150.377 us; speedup vs baseline: 1.1361x; 1.1361x over previous
//
#include <hip/hip_runtime.h>

// NFLinear equivariant layer, closed-form decomposition.
// out0[a,b,:] = w_ih[a,b,:]@th0[0] + A0C[a,:] + B0[b,:]
// out1[a,b,:] = Y[a,b,:]@th1[13] + Y[b,a,:]@th1[11] + A1C[a,:] + B1[b,:] + (a==b)*DD1[a,:]
// out2[b,:]   = vectors(b)@th2 + scalars   (written by k_vec)
//
// k_stage1 (2320 blocks, one reduction phase each) -> k_small (4 blocks, grand
// means) -> k_vec (49 blocks, straight-line) -> k_out (2048 blocks, streams).

#define N0 784
#define N1 512

typedef float v4f __attribute__((ext_vector_type(4)));
typedef float v2f __attribute__((ext_vector_type(2)));

__device__ __forceinline__ float4 f4add(float4 a, float4 b) {
  a.x += b.x; a.y += b.y; a.z += b.z; a.w += b.w; return a;
}
__device__ __forceinline__ void nt_store4(float* p, float4 v) {
  v4f x; x[0] = v.x; x[1] = v.y; x[2] = v.z; x[3] = v.w;
  __builtin_nontemporal_store(x, (v4f*)p);
}
__device__ __forceinline__ void nt_store2(float* p, float x0, float x1) {
  v2f x; x[0] = x0; x[1] = x1;
  __builtin_nontemporal_store(x, (v2f*)p);
}

// grid 2320, one reduction phase per block:
// [0,784): row-mean w_ih -> rm_ih ; [784,1296): col-mean w_ih -> cm_ih
// [1296,1808): row-mean w_hh -> rm_hh ; [1808,2320): col-mean w_hh -> cm_hh + diag
__global__ __launch_bounds__(256)
void k_stage1(const float* __restrict__ wih, const float* __restrict__ whh,
              float* __restrict__ rm_ih, float* __restrict__ cm_ih,
              float* __restrict__ rm_hh, float* __restrict__ cm_hh,
              float* __restrict__ d_hh) {
  __shared__ float4 red[256];
  int t = threadIdx.x, blk = blockIdx.x;
  float4 acc = make_float4(0.f, 0.f, 0.f, 0.f);
  float scale;
  float* dst;
  if (blk < N0) {
    const float4* row = (const float4*)(wih + (size_t)blk * 8192);
    for (int j = t; j < 2048; j += 256) acc = f4add(acc, row[j]);
    scale = 1.f / 512.f; dst = rm_ih + blk * 16;
  } else if (blk < N0 + N1) {
    int b = blk - N0, q = t & 3, g = t >> 2;
    for (int a = g; a < N0; a += 64)
      acc = f4add(acc, *(const float4*)(wih + (size_t)a * 8192 + b * 16 + q * 4));
    scale = 1.f / 784.f; dst = cm_ih + b * 16;
  } else if (blk < N0 + 2 * N1) {
    int b = blk - N0 - N1;
    const float4* row = (const float4*)(whh + (size_t)b * 8192);
    for (int j = t; j < 2048; j += 256) acc = f4add(acc, row[j]);
    scale = 1.f / 512.f; dst = rm_hh + b * 16;
  } else {
    int b = blk - N0 - 2 * N1, q = t & 3, g = t >> 2;
    for (int a = g; a < N1; a += 64)
      acc = f4add(acc, *(const float4*)(whh + (size_t)a * 8192 + b * 16 + q * 4));
    scale = 1.f / 512.f; dst = cm_hh + b * 16;
    if (t < 4) ((float4*)(d_hh + b * 16))[t] = *(const float4*)(whh + (size_t)b * 8192 + b * 16 + t * 4);
  }
  red[t] = acc; __syncthreads();
  #pragma unroll
  for (int s = 128; s >= 4; s >>= 1) {
    if (t < s) red[t] = f4add(red[t], red[t + s]);
    __syncthreads();
  }
  if (t < 4) {  // red[t] = sum over lanes == t (mod 4) -> quad t of the 16-vector
    float4 m = red[t];
    ((float4*)dst)[t] = make_float4(m.x * scale, m.y * scale, m.z * scale, m.w * scale);
  }
}

// grid 4: grand means.  gv_g[0..15]=mean rm_ih, [16..31]=mean d_hh,
// [32..47]=mean rm_hh, [48..63]=mean bvec
__global__ __launch_bounds__(256)
void k_small(const float* __restrict__ rm_ih, const float* __restrict__ d_hh,
             const float* __restrict__ rm_hh, const float* __restrict__ bvec,
             float* __restrict__ gv_g) {
  __shared__ float4 red[256];
  int t = threadIdx.x, q = t & 3, g = t >> 2;
  const float* src; int n; float scale;
  switch (blockIdx.x) {
    case 0: src = rm_ih; n = N0; scale = 1.f / 784.f; break;
    case 1: src = d_hh;  n = N1; scale = 1.f / 512.f; break;
    case 2: src = rm_hh; n = N1; scale = 1.f / 512.f; break;
    default: src = bvec; n = N1; scale = 1.f / 512.f; break;
  }
  float4 acc = make_float4(0.f, 0.f, 0.f, 0.f);
  for (int a = g; a < n; a += 64) acc = f4add(acc, ((const float4*)src)[a * 4 + q]);
  red[t] = acc; __syncthreads();
  #pragma unroll
  for (int s = 128; s >= 4; s >>= 1) {
    if (t < s) red[t] = f4add(red[t], red[t + s]);
    __syncthreads();
  }
  if (t < 4) {
    float4 m = red[t];
    float* dst = gv_g + blockIdx.x * 16 + t * 4;
    dst[0] = m.x * scale; dst[1] = m.y * scale; dst[2] = m.z * scale; dst[3] = m.w * scale;
  }
}

// grid 49: thetas+gv in LDS (one barrier), then straight-line per-thread:
// scalar projections, vector terms, out2.
__global__ __launch_bounds__(256)
void k_vec(const float* __restrict__ rm_ih, const float* __restrict__ cm_ih,
           const float* __restrict__ rm_hh, const float* __restrict__ cm_hh,
           const float* __restrict__ d_hh, const float* __restrict__ bvec,
           const float* __restrict__ gv_g,
           const float* __restrict__ th0, const float* __restrict__ bias0,
           const float* __restrict__ th1, const float* __restrict__ bias1,
           const float* __restrict__ th2, const float* __restrict__ bias2,
           float* __restrict__ A0C, float* __restrict__ B0,
           float* __restrict__ A1C, float* __restrict__ B1,
           float* __restrict__ DD1, float* __restrict__ out2) {
  __shared__ float th[11520];   // th0 @0 (2816), th1 @2816 (6400), th2 @9216 (2304)
  __shared__ float gvs[64];
  int t = threadIdx.x;
  {
    float4* t4 = (float4*)th;
    const float4* s0 = (const float4*)th0;
    const float4* s1 = (const float4*)th1;
    const float4* s2 = (const float4*)th2;
    for (int j = t; j < 704; j += 256) t4[j] = s0[j];
    for (int j = t; j < 1600; j += 256) t4[704 + j] = s1[j];
    for (int j = t; j < 576; j += 256) t4[2304 + j] = s2[j];
    if (t < 64) gvs[t] = gv_g[t];
  }
  __syncthreads();
  int co = t & 15;
  // scalar projections (each thread, straight-line): C0, C1, E1, S2
  float c0 = bias0[co], c1 = bias1[co], e1 = 0.f, s2v = bias2[co];
  #pragma unroll
  for (int j = 0; j < 16; j++) {
    int o = j * 16 + co;
    float g0v = gvs[j], dm = gvs[16 + j], gh = gvs[32 + j], mv = gvs[48 + j];
    c0  += g0v * th[768 + o]         + dm * th[1280 + o]        + gh * th[2048 + o]        + mv * th[2560 + o];
    c1  += g0v * th[2816 + 1024 + o] + dm * th[2816 + 2304 + o] + gh * th[2816 + 4864 + o] + mv * th[2816 + 6144 + o];
    e1  += g0v * th[2816 + 512 + o]  + dm * th[2816 + 1792 + o] + gh * th[2816 + 4096 + o] + mv * th[2816 + 5632 + o];
    s2v += g0v * th[9216 + 256 + o]  + dm * th[9216 + 768 + o]  + gh * th[9216 + 1536 + o] + mv * th[9216 + 2048 + o];
  }
  // vector terms
  int idx = blockIdx.x * 256 + t;
  int i = idx >> 4;
  float a0 = c0;
  {
    const float4* r4 = (const float4*)(rm_ih + i * 16);
    #pragma unroll
    for (int kq = 0; kq < 4; kq++) {
      float4 r = r4[kq];
      float vr[4] = { r.x, r.y, r.z, r.w };
      #pragma unroll
      for (int e = 0; e < 4; e++) a0 += vr[e] * th[256 + (kq * 4 + e) * 16 + co];
    }
  }
  A0C[idx] = a0;
  if (i < N1) {
    float b0a = 0.f, a1 = c1, b1a = 0.f, dd = e1, o2 = s2v;
    const float4* c4 = (const float4*)(cm_ih + i * 16);
    const float4* d4 = (const float4*)(d_hh + i * 16);
    const float4* r4 = (const float4*)(rm_hh + i * 16);
    const float4* m4 = (const float4*)(cm_hh + i * 16);
    const float4* v4 = (const float4*)(bvec + i * 16);
    #pragma unroll
    for (int kq = 0; kq < 4; kq++) {
      float4 cq = c4[kq], dq = d4[kq], rq = r4[kq], mq = m4[kq], vq = v4[kq];
      float vc[4] = { cq.x, cq.y, cq.z, cq.w };
      float vd[4] = { dq.x, dq.y, dq.z, dq.w };
      float vr[4] = { rq.x, rq.y, rq.z, rq.w };
      float vm[4] = { mq.x, mq.y, mq.z, mq.w };
      float vb[4] = { vq.x, vq.y, vq.z, vq.w };
      #pragma unroll
      for (int e = 0; e < 4; e++) {
        int o = (kq * 4 + e) * 16 + co;
        float cmi = vc[e], d = vd[e], r = vr[e], cm = vm[e], v = vb[e];
        b0a += cmi * th[512 + o]         + d * th[1024 + o]        + r * th[1536 + o]        + cm * th[1792 + o]        + v * th[2304 + o];
        a1  += cmi * th[2816 + 768 + o]  + d * th[2816 + 2048 + o] + r * th[2816 + 4352 + o] + cm * th[2816 + 4608 + o] + v * th[2816 + 5888 + o];
        b1a += cmi * th[2816 + 256 + o]  + d * th[2816 + 1536 + o] + r * th[2816 + 3072 + o] + cm * th[2816 + 3840 + o] + v * th[2816 + 5376 + o];
        dd  += cmi * th[2816 + 0 + o]    + d * th[2816 + 1280 + o] + r * th[2816 + 2560 + o] + cm * th[2816 + 3584 + o] + v * th[2816 + 5120 + o];
        o2  += cmi * th[9216 + 0 + o]    + d * th[9216 + 512 + o]  + r * th[9216 + 1024 + o] + cm * th[9216 + 1280 + o] + v * th[9216 + 1792 + o];
      }
    }
    B0[idx] = b0a; A1C[idx] = a1; B1[idx] = b1a; DD1[idx] = dd; out2[idx] = o2;
  }
}

// grid 2048: blocks [0,1024) stream out0; [1024,2048) stream out1.
__global__ __launch_bounds__(256)
void k_out(const float* __restrict__ wih, const float* __restrict__ whh,
           const float* __restrict__ th0, const float* __restrict__ th1,
           const float* __restrict__ A0C, const float* __restrict__ B0,
           const float* __restrict__ A1C, const float* __restrict__ B1,
           const float* __restrict__ DD1,
           float* __restrict__ out0, float* __restrict__ out1) {
  if (blockIdx.x < 1024) {
    int tid = blockIdx.x * 256 + threadIdx.x;
    int q = tid & 3;
    int slot = tid >> 2;
    const int nslots = (1024 * 256) >> 2;
    float4 tq[16];
    #pragma unroll
    for (int k = 0; k < 16; k++) tq[k] = *(const float4*)(th0 + k * 16 + q * 4);
    for (int p = slot; p < N0 * N1; p += nslots) {
      const float4* row = (const float4*)(wih + (size_t)p * 16);
      float4 r0 = row[0], r1 = row[1], r2 = row[2], r3 = row[3];
      int a = p >> 9, bb = p & 511;
      float4 acc = *(const float4*)(A0C + a * 16 + q * 4);
      float4 b4 = *(const float4*)(B0 + bb * 16 + q * 4);
      acc.x += b4.x; acc.y += b4.y; acc.z += b4.z; acc.w += b4.w;
      float wv[16] = { r0.x, r0.y, r0.z, r0.w, r1.x, r1.y, r1.z, r1.w,
                       r2.x, r2.y, r2.z, r2.w, r3.x, r3.y, r3.z, r3.w };
      #pragma unroll
      for (int k = 0; k < 16; k++) {
        acc.x += wv[k] * tq[k].x; acc.y += wv[k] * tq[k].y;
        acc.z += wv[k] * tq[k].z; acc.w += wv[k] * tq[k].w;
      }
      nt_store4(out0 + (size_t)p * 16 + q * 4, acc);
    }
  } else {
    int tid = (blockIdx.x - 1024) * 256 + threadIdx.x;
    int q = tid & 7;
    int slot = tid >> 3;
    const int nslots = (1024 * 256) >> 3;
    float2 tA[16], tB[16];
    #pragma unroll
    for (int k = 0; k < 16; k++) {
      tA[k] = *(const float2*)(th1 + 13 * 256 + k * 16 + q * 2);
      tB[k] = *(const float2*)(th1 + 11 * 256 + k * 16 + q * 2);
    }
    for (int p = slot; p < N1 * N1; p += nslots) {
      int a = p >> 9, b = p & 511;
      const float4* ra = (const float4*)(whh + (size_t)p * 16);
      const float4* rt = (const float4*)(whh + (size_t)((b << 9) | a) * 16);
      float4 a0 = ra[0], a1v = ra[1], a2 = ra[2], a3 = ra[3];
      float4 t0 = rt[0], t1v = rt[1], t2 = rt[2], t3 = rt[3];
      float2 acc = *(const float2*)(A1C + a * 16 + q * 2);
      float2 bb = *(const float2*)(B1 + b * 16 + q * 2);
      acc.x += bb.x; acc.y += bb.y;
      if (a == b) {
        float2 dd = *(const float2*)(DD1 + a * 16 + q * 2);
        acc.x += dd.x; acc.y += dd.y;
      }
      float ya[16] = { a0.x, a0.y, a0.z, a0.w, a1v.x, a1v.y, a1v.z, a1v.w,
                       a2.x, a2.y, a2.z, a2.w, a3.x, a3.y, a3.z, a3.w };
      float yt[16] = { t0.x, t0.y, t0.z, t0.w, t1v.x, t1v.y, t1v.z, t1v.w,
                       t2.x, t2.y, t2.z, t2.w, t3.x, t3.y, t3.z, t3.w };
      #pragma unroll
      for (int k = 0; k < 16; k++) {
        acc.x += ya[k] * tA[k].x + yt[k] * tB[k].x;
        acc.y += ya[k] * tA[k].y + yt[k] * tB[k].y;
      }
      nt_store2(out1 + (size_t)p * 16 + q * 2, acc.x, acc.y);
    }
  }
}

extern "C" void kernel_launch(void* const* d_in, const int* in_sizes, int n_in,
                              void* d_out, int out_size, void* d_ws, size_t ws_size,
                              hipStream_t stream) {
  const float* w_ih = (const float*)d_in[0];
  const float* w_hh = (const float*)d_in[1];
  const float* bvec = (const float*)d_in[2];
  const float *th0, *bias0, *th1, *bias1, *th2, *bias2;
  if (n_in >= 9 && in_sizes[4] == 16) {  // dict order
    th0 = (const float*)d_in[3]; bias0 = (const float*)d_in[4];
    th1 = (const float*)d_in[5]; bias1 = (const float*)d_in[6];
    th2 = (const float*)d_in[7]; bias2 = (const float*)d_in[8];
  } else {  // signature order
    th0 = (const float*)d_in[3]; th1 = (const float*)d_in[4]; th2 = (const float*)d_in[5];
    bias0 = (const float*)d_in[6]; bias1 = (const float*)d_in[7]; bias2 = (const float*)d_in[8];
  }
  float* ws    = (float*)d_ws;
  float* rm_ih = ws;               // 12544
  float* cm_ih = rm_ih + 12544;    // 8192
  float* rm_hh = cm_ih + 8192;
  float* cm_hh = rm_hh + 8192;
  float* d_hh  = cm_hh + 8192;
  float* A0C   = d_hh + 8192;      // 12544
  float* B0    = A0C + 12544;
  float* A1C   = B0 + 8192;
  float* B1    = A1C + 8192;
  float* DD1   = B1 + 8192;
  float* gv_g  = DD1 + 8192;       // 64
  float* out0 = (float*)d_out;
  float* out1 = out0 + (size_t)N0 * N1 * 16;
  float* out2 = out1 + (size_t)N1 * N1 * 16;

  hipLaunchKernelGGL(k_stage1, dim3(N0 + 3 * N1), dim3(256), 0, stream,
                     w_ih, w_hh, rm_ih, cm_ih, rm_hh, cm_hh, d_hh);
  hipLaunchKernelGGL(k_small, dim3(4), dim3(256), 0, stream,
                     rm_ih, d_hh, rm_hh, bvec, gv_g);
  hipLaunchKernelGGL(k_vec, dim3(49), dim3(256), 0, stream,
                     rm_ih, cm_ih, rm_hh, cm_hh, d_hh, bvec, gv_g,
                     th0, bias0, th1, bias1, th2, bias2,
                     A0C, B0, A1C, B1, DD1, out2);
  hipLaunchKernelGGL(k_out, dim3(2048), dim3(256), 0, stream,
                     w_ih, w_hh, th0, th1, A0C, B0, A1C, B1, DD1, out0, out1);
}

// Round 6
// 147.931 us; speedup vs baseline: 1.1549x; 1.0165x over previous
//
#include <hip/hip_runtime.h>

// NFLinear equivariant layer, closed-form decomposition.
// out0[a,b,:] = w_ih[a,b,:]@th0[0] + A0C[a,:] + B0[b,:]
// out1[a,b,:] = Y[a,b,:]@th1[13] + Y[b,a,:]@th1[11] + A1C[a,:] + B1[b,:] + (a==b)*DD1[a,:]
// out2[b,:]   = vectors(b)@th2 + scalars   (written by k_vec)
//
// k_stage1 (324 blocks): single pass over each W; row means + diag direct,
//   column sums as per-band partials in ws (deterministic).
// k_red (68 blocks x 1024): coalesced partial->cm reduction + 4 grand means.
// k_vec (49 blocks): straight-line scalar projections + vector terms + out2.
// k_out (3072 blocks): both output streams, thetas in LDS (low VGPR -> high
//   occupancy to hide the out1 transpose-read latency).

#define N0 784
#define N1 512
#define RPB 4
#define NB_IH (N0 / RPB)   // 196
#define NB_HH (N1 / RPB)   // 128

typedef float v4f __attribute__((ext_vector_type(4)));
typedef float v2f __attribute__((ext_vector_type(2)));

__device__ __forceinline__ float4 f4add(float4 a, float4 b) {
  a.x += b.x; a.y += b.y; a.z += b.z; a.w += b.w; return a;
}
__device__ __forceinline__ void nt_store4(float* p, float4 v) {
  v4f x; x[0] = v.x; x[1] = v.y; x[2] = v.z; x[3] = v.w;
  __builtin_nontemporal_store(x, (v4f*)p);
}
__device__ __forceinline__ void nt_store2(float* p, float x0, float x1) {
  v2f x; x[0] = x0; x[1] = x1;
  __builtin_nontemporal_store(x, (v2f*)p);
}

// grid 324: [0,196) w_ih 4-row bands; [196,324) w_hh 4-row bands (+ diag).
__global__ __launch_bounds__(256)
void k_stage1(const float* __restrict__ wih, const float* __restrict__ whh,
              float* __restrict__ rm_ih, float* __restrict__ rm_hh,
              float* __restrict__ d_hh,
              float* __restrict__ part_ih, float* __restrict__ part_hh) {
  __shared__ float4 colacc[2048];       // 32 KB: column sums of this band
  __shared__ float4 redAll[RPB][256];   // 16 KB: row-sum trees
  int t = threadIdx.x, blk = blockIdx.x;
  bool hh = blk >= NB_IH;
  const float* W = hh ? whh : wih;
  float* rm      = hh ? rm_hh : rm_ih;
  float* part    = hh ? part_hh : part_ih;
  int pblk = hh ? blk - NB_IH : blk;
  int r0 = pblk * RPB;

  #pragma unroll
  for (int jj = 0; jj < 8; jj++) colacc[t + jj * 256] = make_float4(0.f, 0.f, 0.f, 0.f);
  // colacc[j] only touched by thread t == j%256: no barrier needed.
  #pragma unroll
  for (int r = 0; r < RPB; r++) {
    const float4* row = (const float4*)(W + (size_t)(r0 + r) * 8192);
    float4 v[8];
    #pragma unroll
    for (int jj = 0; jj < 8; jj++) v[jj] = row[t + jj * 256];   // 8 loads in flight
    float4 racc = make_float4(0.f, 0.f, 0.f, 0.f);
    #pragma unroll
    for (int jj = 0; jj < 8; jj++) {
      colacc[t + jj * 256] = f4add(colacc[t + jj * 256], v[jj]);
      racc = f4add(racc, v[jj]);
    }
    redAll[r][t] = racc;
  }
  __syncthreads();
  #pragma unroll
  for (int s = 128; s >= 4; s >>= 1) {
    if (t < s) {
      #pragma unroll
      for (int r = 0; r < RPB; r++) redAll[r][t] = f4add(redAll[r][t], redAll[r][t + s]);
    }
    __syncthreads();
  }
  if (t < 16) {   // row r=t>>2, quad q=t&3 (lane-class mod 4 == quad)
    int r = t >> 2, q = t & 3;
    float4 m = redAll[r][q];
    const float s = 1.f / 512.f;
    ((float4*)(rm + (r0 + r) * 16))[q] = make_float4(m.x * s, m.y * s, m.z * s, m.w * s);
  }
  if (hh && t < 64) {
    int r = t >> 4, ci = t & 15;
    d_hh[(r0 + r) * 16 + ci] = whh[(size_t)(r0 + r) * 8192 + (r0 + r) * 16 + ci];
  }
  float4* p4 = (float4*)(part + (size_t)pblk * 8192);
  #pragma unroll
  for (int jj = 0; jj < 8; jj++) p4[t + jj * 256] = colacc[t + jj * 256];
}

// grid 68 x 1024: [0,32) cm_ih chunks, [32,64) cm_hh chunks, [64,68) grand means.
__global__ __launch_bounds__(1024)
void k_red(const float* __restrict__ part_ih, const float* __restrict__ part_hh,
           const float* __restrict__ rm_ih, const float* __restrict__ rm_hh,
           const float* __restrict__ d_hh, const float* __restrict__ bvec,
           float* __restrict__ cm_ih, float* __restrict__ cm_hh,
           float* __restrict__ gv_g) {
  __shared__ float lds[1024];
  __shared__ float4 red4[1024];
  int t = threadIdx.x, blk = blockIdx.x;
  if (blk < 64) {
    bool hh = blk >= 32;
    int j = hh ? blk - 32 : blk;                 // 256-float chunk index
    const float* part = hh ? part_hh : part_ih;
    int nP = hh ? NB_HH : NB_IH;
    float scale = hh ? (1.f / 512.f) : (1.f / 784.f);
    float* cm = hh ? cm_hh : cm_ih;
    int sub = t & 255, py = t >> 8;              // 4 p-chunks
    int per = (nP + 3) >> 2;
    int p0 = py * per;
    int p1 = p0 + per; if (p1 > nP) p1 = nP;
    float acc = 0.f;
    for (int p = p0; p < p1; p++) acc += part[(size_t)p * 8192 + j * 256 + sub];
    lds[t] = acc; __syncthreads();
    if (py == 0)
      cm[j * 256 + sub] = (lds[sub] + lds[256 + sub] + lds[512 + sub] + lds[768 + sub]) * scale;
  } else {
    int which = blk - 64;
    const float* src; int n; float scale;
    switch (which) {
      case 0:  src = rm_ih; n = N0; scale = 1.f / 784.f; break;
      case 1:  src = d_hh;  n = N1; scale = 1.f / 512.f; break;
      case 2:  src = rm_hh; n = N1; scale = 1.f / 512.f; break;
      default: src = bvec;  n = N1; scale = 1.f / 512.f; break;
    }
    int q = t & 3, g = t >> 2;
    float4 acc = make_float4(0.f, 0.f, 0.f, 0.f);
    for (int a = g; a < n; a += 256) acc = f4add(acc, ((const float4*)src)[a * 4 + q]);
    red4[t] = acc; __syncthreads();
    #pragma unroll
    for (int s = 512; s >= 4; s >>= 1) {
      if (t < s) red4[t] = f4add(red4[t], red4[t + s]);
      __syncthreads();
    }
    if (t < 4) {
      float4 m = red4[t];
      float* dst = gv_g + which * 16 + t * 4;
      dst[0] = m.x * scale; dst[1] = m.y * scale; dst[2] = m.z * scale; dst[3] = m.w * scale;
    }
  }
}

// grid 49: thetas+gv in LDS (one barrier), straight-line per-thread.
__global__ __launch_bounds__(256)
void k_vec(const float* __restrict__ rm_ih, const float* __restrict__ cm_ih,
           const float* __restrict__ rm_hh, const float* __restrict__ cm_hh,
           const float* __restrict__ d_hh, const float* __restrict__ bvec,
           const float* __restrict__ gv_g,
           const float* __restrict__ th0, const float* __restrict__ bias0,
           const float* __restrict__ th1, const float* __restrict__ bias1,
           const float* __restrict__ th2, const float* __restrict__ bias2,
           float* __restrict__ A0C, float* __restrict__ B0,
           float* __restrict__ A1C, float* __restrict__ B1,
           float* __restrict__ DD1, float* __restrict__ out2) {
  __shared__ float th[11520];   // th0 @0 (2816), th1 @2816 (6400), th2 @9216 (2304)
  __shared__ float gvs[64];
  int t = threadIdx.x;
  {
    float4* t4 = (float4*)th;
    const float4* s0 = (const float4*)th0;
    const float4* s1 = (const float4*)th1;
    const float4* s2 = (const float4*)th2;
    for (int j = t; j < 704; j += 256) t4[j] = s0[j];
    for (int j = t; j < 1600; j += 256) t4[704 + j] = s1[j];
    for (int j = t; j < 576; j += 256) t4[2304 + j] = s2[j];
    if (t < 64) gvs[t] = gv_g[t];
  }
  __syncthreads();
  int co = t & 15;
  float c0 = bias0[co], c1 = bias1[co], e1 = 0.f, s2v = bias2[co];
  #pragma unroll
  for (int j = 0; j < 16; j++) {
    int o = j * 16 + co;
    float g0v = gvs[j], dm = gvs[16 + j], gh = gvs[32 + j], mv = gvs[48 + j];
    c0  += g0v * th[768 + o]         + dm * th[1280 + o]        + gh * th[2048 + o]        + mv * th[2560 + o];
    c1  += g0v * th[2816 + 1024 + o] + dm * th[2816 + 2304 + o] + gh * th[2816 + 4864 + o] + mv * th[2816 + 6144 + o];
    e1  += g0v * th[2816 + 512 + o]  + dm * th[2816 + 1792 + o] + gh * th[2816 + 4096 + o] + mv * th[2816 + 5632 + o];
    s2v += g0v * th[9216 + 256 + o]  + dm * th[9216 + 768 + o]  + gh * th[9216 + 1536 + o] + mv * th[9216 + 2048 + o];
  }
  int idx = blockIdx.x * 256 + t;
  int i = idx >> 4;
  float a0 = c0;
  {
    const float4* r4 = (const float4*)(rm_ih + i * 16);
    #pragma unroll
    for (int kq = 0; kq < 4; kq++) {
      float4 r = r4[kq];
      float vr[4] = { r.x, r.y, r.z, r.w };
      #pragma unroll
      for (int e = 0; e < 4; e++) a0 += vr[e] * th[256 + (kq * 4 + e) * 16 + co];
    }
  }
  A0C[idx] = a0;
  if (i < N1) {
    float b0a = 0.f, a1 = c1, b1a = 0.f, dd = e1, o2 = s2v;
    const float4* c4 = (const float4*)(cm_ih + i * 16);
    const float4* d4 = (const float4*)(d_hh + i * 16);
    const float4* r4 = (const float4*)(rm_hh + i * 16);
    const float4* m4 = (const float4*)(cm_hh + i * 16);
    const float4* v4 = (const float4*)(bvec + i * 16);
    #pragma unroll
    for (int kq = 0; kq < 4; kq++) {
      float4 cq = c4[kq], dq = d4[kq], rq = r4[kq], mq = m4[kq], vq = v4[kq];
      float vc[4] = { cq.x, cq.y, cq.z, cq.w };
      float vd[4] = { dq.x, dq.y, dq.z, dq.w };
      float vr[4] = { rq.x, rq.y, rq.z, rq.w };
      float vm[4] = { mq.x, mq.y, mq.z, mq.w };
      float vb[4] = { vq.x, vq.y, vq.z, vq.w };
      #pragma unroll
      for (int e = 0; e < 4; e++) {
        int o = (kq * 4 + e) * 16 + co;
        float cmi = vc[e], d = vd[e], r = vr[e], cm = vm[e], v = vb[e];
        b0a += cmi * th[512 + o]         + d * th[1024 + o]        + r * th[1536 + o]        + cm * th[1792 + o]        + v * th[2304 + o];
        a1  += cmi * th[2816 + 768 + o]  + d * th[2816 + 2048 + o] + r * th[2816 + 4352 + o] + cm * th[2816 + 4608 + o] + v * th[2816 + 5888 + o];
        b1a += cmi * th[2816 + 256 + o]  + d * th[2816 + 1536 + o] + r * th[2816 + 3072 + o] + cm * th[2816 + 3840 + o] + v * th[2816 + 5376 + o];
        dd  += cmi * th[2816 + 0 + o]    + d * th[2816 + 1280 + o] + r * th[2816 + 2560 + o] + cm * th[2816 + 3584 + o] + v * th[2816 + 5120 + o];
        o2  += cmi * th[9216 + 0 + o]    + d * th[9216 + 512 + o]  + r * th[9216 + 1024 + o] + cm * th[9216 + 1280 + o] + v * th[9216 + 1792 + o];
      }
    }
    B0[idx] = b0a; A1C[idx] = a1; B1[idx] = b1a; DD1[idx] = dd; out2[idx] = o2;
  }
}

// grid 3072: [0,1024) out0; [1024,3072) out1. Thetas in LDS -> low VGPR.
__global__ __launch_bounds__(256)
void k_out(const float* __restrict__ wih, const float* __restrict__ whh,
           const float* __restrict__ th0, const float* __restrict__ th1,
           const float* __restrict__ A0C, const float* __restrict__ B0,
           const float* __restrict__ A1C, const float* __restrict__ B1,
           const float* __restrict__ DD1,
           float* __restrict__ out0, float* __restrict__ out1) {
  __shared__ float t0s[256];
  __shared__ float tAs[256];
  __shared__ float tBs[256];
  int t = threadIdx.x;
  if (blockIdx.x < 1024) {
    t0s[t] = th0[t];
    __syncthreads();
    int tid = blockIdx.x * 256 + t;
    int q = tid & 3;
    int slot = tid >> 2;
    const int nslots = (1024 * 256) >> 2;
    for (int p = slot; p < N0 * N1; p += nslots) {
      const float4* row = (const float4*)(wih + (size_t)p * 16);
      float4 r0 = row[0], r1 = row[1], r2 = row[2], r3 = row[3];
      int a = p >> 9, bb = p & 511;
      float4 acc = *(const float4*)(A0C + a * 16 + q * 4);
      float4 b4 = *(const float4*)(B0 + bb * 16 + q * 4);
      acc.x += b4.x; acc.y += b4.y; acc.z += b4.z; acc.w += b4.w;
      float wv[16] = { r0.x, r0.y, r0.z, r0.w, r1.x, r1.y, r1.z, r1.w,
                       r2.x, r2.y, r2.z, r2.w, r3.x, r3.y, r3.z, r3.w };
      #pragma unroll
      for (int k = 0; k < 16; k++) {
        float4 tq = *(const float4*)(t0s + k * 16 + q * 4);
        acc.x += wv[k] * tq.x; acc.y += wv[k] * tq.y;
        acc.z += wv[k] * tq.z; acc.w += wv[k] * tq.w;
      }
      nt_store4(out0 + (size_t)p * 16 + q * 4, acc);
    }
  } else {
    tAs[t] = th1[13 * 256 + t];
    tBs[t] = th1[11 * 256 + t];
    __syncthreads();
    int tid = (blockIdx.x - 1024) * 256 + t;
    int q = tid & 7;
    int slot = tid >> 3;
    const int nslots = (2048 * 256) >> 3;
    for (int p = slot; p < N1 * N1; p += nslots) {
      int a = p >> 9, b = p & 511;
      const float4* ra = (const float4*)(whh + (size_t)p * 16);
      const float4* rt = (const float4*)(whh + (size_t)((b << 9) | a) * 16);
      float4 a0 = ra[0], a1v = ra[1], a2 = ra[2], a3 = ra[3];
      float4 t0 = rt[0], t1v = rt[1], t2 = rt[2], t3 = rt[3];
      float2 acc = *(const float2*)(A1C + a * 16 + q * 2);
      float2 bb = *(const float2*)(B1 + b * 16 + q * 2);
      acc.x += bb.x; acc.y += bb.y;
      if (a == b) {
        float2 dd = *(const float2*)(DD1 + a * 16 + q * 2);
        acc.x += dd.x; acc.y += dd.y;
      }
      float ya[16] = { a0.x, a0.y, a0.z, a0.w, a1v.x, a1v.y, a1v.z, a1v.w,
                       a2.x, a2.y, a2.z, a2.w, a3.x, a3.y, a3.z, a3.w };
      float yt[16] = { t0.x, t0.y, t0.z, t0.w, t1v.x, t1v.y, t1v.z, t1v.w,
                       t2.x, t2.y, t2.z, t2.w, t3.x, t3.y, t3.z, t3.w };
      #pragma unroll
      for (int k = 0; k < 16; k++) {
        float2 tA = *(const float2*)(tAs + k * 16 + q * 2);
        float2 tB = *(const float2*)(tBs + k * 16 + q * 2);
        acc.x += ya[k] * tA.x + yt[k] * tB.x;
        acc.y += ya[k] * tA.y + yt[k] * tB.y;
      }
      nt_store2(out1 + (size_t)p * 16 + q * 2, acc.x, acc.y);
    }
  }
}

extern "C" void kernel_launch(void* const* d_in, const int* in_sizes, int n_in,
                              void* d_out, int out_size, void* d_ws, size_t ws_size,
                              hipStream_t stream) {
  const float* w_ih = (const float*)d_in[0];
  const float* w_hh = (const float*)d_in[1];
  const float* bvec = (const float*)d_in[2];
  const float *th0, *bias0, *th1, *bias1, *th2, *bias2;
  if (n_in >= 9 && in_sizes[4] == 16) {  // dict order
    th0 = (const float*)d_in[3]; bias0 = (const float*)d_in[4];
    th1 = (const float*)d_in[5]; bias1 = (const float*)d_in[6];
    th2 = (const float*)d_in[7]; bias2 = (const float*)d_in[8];
  } else {  // signature order
    th0 = (const float*)d_in[3]; th1 = (const float*)d_in[4]; th2 = (const float*)d_in[5];
    bias0 = (const float*)d_in[6]; bias1 = (const float*)d_in[7]; bias2 = (const float*)d_in[8];
  }
  float* ws      = (float*)d_ws;
  float* rm_ih   = ws;                      // 12544
  float* rm_hh   = rm_ih + 12544;           // 8192
  float* d_hh    = rm_hh + 8192;            // 8192
  float* cm_ih   = d_hh + 8192;             // 8192
  float* cm_hh   = cm_ih + 8192;            // 8192
  float* A0C     = cm_hh + 8192;            // 12544
  float* B0      = A0C + 12544;             // 8192
  float* A1C     = B0 + 8192;               // 8192
  float* B1      = A1C + 8192;              // 8192
  float* DD1     = B1 + 8192;               // 8192
  float* gv_g    = DD1 + 8192;              // 64 (+ pad)
  float* part_ih = gv_g + 128;              // 196*8192
  float* part_hh = part_ih + (size_t)NB_IH * 8192;  // 128*8192
  float* out0 = (float*)d_out;
  float* out1 = out0 + (size_t)N0 * N1 * 16;
  float* out2 = out1 + (size_t)N1 * N1 * 16;

  hipLaunchKernelGGL(k_stage1, dim3(NB_IH + NB_HH), dim3(256), 0, stream,
                     w_ih, w_hh, rm_ih, rm_hh, d_hh, part_ih, part_hh);
  hipLaunchKernelGGL(k_red, dim3(68), dim3(1024), 0, stream,
                     part_ih, part_hh, rm_ih, rm_hh, d_hh, bvec,
                     cm_ih, cm_hh, gv_g);
  hipLaunchKernelGGL(k_vec, dim3(49), dim3(256), 0, stream,
                     rm_ih, cm_ih, rm_hh, cm_hh, d_hh, bvec, gv_g,
                     th0, bias0, th1, bias1, th2, bias2,
                     A0C, B0, A1C, B1, DD1, out2);
  hipLaunchKernelGGL(k_out, dim3(3072), dim3(256), 0, stream,
                     w_ih, w_hh, th0, th1, A0C, B0, A1C, B1, DD1, out0, out1);
}